// Round 1
// baseline (1680.166 us; speedup 1.0000x reference)
//
#include <hip/hip_runtime.h>
#include <math.h>

#define NIMG 12        // B*N
#define NCH  256       // FC
#define FH   32
#define FW   88
#define NPIX 2816      // FH*FW
#define NDEP 20        // depth bins: 1,4,...,58
#define NOUTC 128
#define NVOX 65536     // 256*256
#define BEV_FLOATS 16777216u  // 2*128*65536

// ---- workspace layout (float offsets) ----
#define WS_MATS    0u          // 12*24
#define WS_A1      512u        // 256
#define WS_C1      768u
#define WS_A2      1024u
#define WS_C2      1280u
#define WS_VCODE   2048u       // 675840 ints
#define WS_ACT1    1048576u    // 8650752
#define WS_ACT2    9699328u    // 8650752
#define WS_FEATT   18350080u   // 12*2816*128 = 4325376
#define WS_MU      22675456u   // 33792
#define WS_LS      22709248u   // 33792  (end 22743040 floats = ~91 MB)
#define WS_BEVTMP  1048576u    // 16777216 floats; ALIASES ACT1/ACT2 (dead after conv3)

__device__ __forceinline__ void inv3x3(const float* __restrict__ M, float* __restrict__ o) {
    float a=M[0],b=M[1],c=M[2],d=M[3],e=M[4],f=M[5],g=M[6],h=M[7],i=M[8];
    float A = e*i - f*h;
    float B = c*h - b*i;
    float C = b*f - c*e;
    float D = f*g - d*i;
    float E = a*i - c*g;
    float F = c*d - a*f;
    float G = d*h - e*g;
    float H = b*g - a*h;
    float I = a*e - b*d;
    float det = a*A + b*D + c*G;
    float id = 1.0f / det;
    o[0]=A*id; o[1]=B*id; o[2]=C*id;
    o[3]=D*id; o[4]=E*id; o[5]=F*id;
    o[6]=G*id; o[7]=H*id; o[8]=I*id;
}

// ---- kernel 0: per-(b,n) matrices + folded BN coefficients ----
__global__ __launch_bounds__(256) void prep_kernel(
    const float* __restrict__ c2e_rot, const float* __restrict__ c2e_trans,
    const float* __restrict__ intrins, const float* __restrict__ post_rot,
    const float* __restrict__ post_trans,
    const float* __restrict__ c1b, const float* __restrict__ s1,
    const float* __restrict__ bb1, const float* __restrict__ m1, const float* __restrict__ v1,
    const float* __restrict__ c2b, const float* __restrict__ s2,
    const float* __restrict__ bb2, const float* __restrict__ m2, const float* __restrict__ v2,
    float* __restrict__ ws)
{
    int t = threadIdx.x;
    if (t < NIMG) {
        float ip[9], ki[9], comb[9];
        inv3x3(post_rot + t*9, ip);
        inv3x3(intrins  + t*9, ki);
        const float* R = c2e_rot + t*9;
        #pragma unroll
        for (int r = 0; r < 3; ++r)
            #pragma unroll
            for (int c = 0; c < 3; ++c)
                comb[r*3+c] = R[r*3+0]*ki[0*3+c] + R[r*3+1]*ki[1*3+c] + R[r*3+2]*ki[2*3+c];
        float* M = ws + WS_MATS + t*24;
        #pragma unroll
        for (int k = 0; k < 9; ++k) { M[k] = ip[k]; M[9+k] = comb[k]; }
        M[18] = c2e_trans[t*3+0]; M[19] = c2e_trans[t*3+1]; M[20] = c2e_trans[t*3+2];
        M[21] = post_trans[t*3+0]; M[22] = post_trans[t*3+1]; M[23] = post_trans[t*3+2];
    }
    // BN folding: out = conv*inv + (b - mean)*inv + beta
    {
        float i1 = s1[t] / sqrtf(v1[t] + 1e-3f);
        ws[WS_A1 + t] = i1;
        ws[WS_C1 + t] = (c1b[t] - m1[t]) * i1 + bb1[t];
        float i2 = s2[t] / sqrtf(v2[t] + 1e-3f);
        ws[WS_A2 + t] = i2;
        ws[WS_C2 + t] = (c2b[t] - m2[t]) * i2 + bb2[t];
    }
}

// ---- kernel 1: voxel code per frustum point ----
__global__ __launch_bounds__(256) void geom_kernel(
    const float* __restrict__ mats, int* __restrict__ vcode)
{
    int i = blockIdx.x * 256 + threadIdx.x;   // 0 .. 675839
    if (i >= NIMG * NDEP * NPIX) return;
    int hw  = i % NPIX;
    int tmp = i / NPIX;
    int d   = tmp % NDEP;
    int bn  = tmp / NDEP;
    int h = hw / FW, w = hw - h * FW;
    const float* M = mats + bn * 24;
    float xs = (float)w * (703.0f / 87.0f);
    float ys = (float)h * (255.0f / 31.0f);
    float dv = 1.0f + 3.0f * (float)d;
    float fx = xs - M[21], fy = ys - M[22], fz = dv - M[23];
    float p0 = M[0]*fx + M[1]*fy + M[2]*fz;
    float p1 = M[3]*fx + M[4]*fy + M[5]*fz;
    float p2 = M[6]*fx + M[7]*fy + M[8]*fz;
    p0 *= p2; p1 *= p2;
    float gx = M[ 9]*p0 + M[10]*p1 + M[11]*p2 + M[18];
    float gy = M[12]*p0 + M[13]*p1 + M[14]*p2 + M[19];
    float gz = M[15]*p0 + M[16]*p1 + M[17]*p2 + M[20];
    // reference: ((geom - (bx - dx/2)) / dx).astype(int32)  -> trunc toward zero
    const float cx = -51.0f - 0.2f, cy = -51.0f - 0.2f, cz = 0.0f - 10.0f;
    int ix = (int)((gx - cx) / 0.4f);
    int iy = (int)((gy - cy) / 0.4f);
    int iz = (int)((gz - cz) / 20.0f);
    bool kept = (ix >= 0) && (ix < 256) && (iy >= 0) && (iy < 256) && (iz == 0);
    vcode[i] = kept ? ((ix << 8) | iy) : -1;
}

// ---- kernel 2: 3x3 conv + folded BN + ReLU ----
// grid (12 images, 64 groups of 4 out-channels), block 256.
// thread t: row r = t>>3, cols (t&7)*11 .. +10 (88 = 8*11).
__global__ __launch_bounds__(256) void conv3x3_bn_relu(
    const float* __restrict__ in,   // [12][256][32][88]
    const float* __restrict__ wgt,  // [256][256][3][3]
    const float* __restrict__ A,    // [256]
    const float* __restrict__ C,    // [256]
    float* __restrict__ out)        // [12][256][32][88]
{
    __shared__ float lds[34 * 91];
    int bn  = blockIdx.x;
    int cog = blockIdx.y;
    int t   = threadIdx.x;
    int r   = t >> 3;
    int c0  = (t & 7) * 11;
    // zero halo (rows 0/33, cols 0 and 89; col 90 is padding)
    for (int i = t; i < 34 * 91; i += 256) {
        int hr = i / 91, hc = i - hr * 91;
        if (hr == 0 || hr == 33 || hc == 0 || hc >= 89) lds[i] = 0.0f;
    }
    // hoisted LDS-write offsets for the stage loop
    int loff[11];
    #pragma unroll
    for (int i = 0; i < 11; ++i) {
        int idx = t + i * 256;
        int hh = idx / FW, ww = idx - hh * FW;
        loff[i] = (hh + 1) * 91 + (ww + 1);
    }
    float acc[44];
    #pragma unroll
    for (int k = 0; k < 44; ++k) acc[k] = 0.0f;
    const float* inp = in + (size_t)bn * NCH * NPIX;
    int co_base = cog * 4;

    for (int ci = 0; ci < NCH; ++ci) {
        __syncthreads();
        const float* p = inp + ci * NPIX;
        #pragma unroll
        for (int i = 0; i < 11; ++i) lds[loff[i]] = p[t + i * 256];
        __syncthreads();
        float w0[13], w1[13], w2[13];
        #pragma unroll
        for (int dx = 0; dx < 13; ++dx) {
            w0[dx] = lds[(r + 0) * 91 + c0 + dx];
            w1[dx] = lds[(r + 1) * 91 + c0 + dx];
            w2[dx] = lds[(r + 2) * 91 + c0 + dx];
        }
        #pragma unroll
        for (int q = 0; q < 4; ++q) {
            const float* wp = wgt + ((size_t)(co_base + q) * NCH + ci) * 9;
            float k00=wp[0],k01=wp[1],k02=wp[2],k10=wp[3],k11=wp[4],k12=wp[5],k20=wp[6],k21=wp[7],k22=wp[8];
            #pragma unroll
            for (int j = 0; j < 11; ++j) {
                float s = acc[q * 11 + j];
                s = fmaf(w0[j  ], k00, s);
                s = fmaf(w0[j+1], k01, s);
                s = fmaf(w0[j+2], k02, s);
                s = fmaf(w1[j  ], k10, s);
                s = fmaf(w1[j+1], k11, s);
                s = fmaf(w1[j+2], k12, s);
                s = fmaf(w2[j  ], k20, s);
                s = fmaf(w2[j+1], k21, s);
                s = fmaf(w2[j+2], k22, s);
                acc[q * 11 + j] = s;
            }
        }
    }
    #pragma unroll
    for (int q = 0; q < 4; ++q) {
        int co = co_base + q;
        float Aa = A[co], Cc = C[co];
        float* op = out + ((size_t)bn * NCH + co) * NPIX + r * FW + c0;
        #pragma unroll
        for (int j = 0; j < 11; ++j) {
            float v = fmaf(acc[q * 11 + j], Aa, Cc);
            op[j] = fmaxf(v, 0.0f);
        }
    }
}

// ---- kernel 3: 1x1 conv (256->130), split into mu / log_sigma / transposed feats ----
// grid (12, 11 pixel-blocks, 5 co-chunks), block 256; thread owns one pixel.
__global__ __launch_bounds__(256) void conv1x1_kernel(
    const float* __restrict__ act2,   // [12][256][2816]
    const float* __restrict__ w3,     // [130][256]
    const float* __restrict__ b3,     // [130]
    float* __restrict__ feat_t,       // [33792][128]
    float* __restrict__ mu,           // [33792]
    float* __restrict__ ls)           // [33792]
{
    __shared__ float wl[32 * 256];
    int bn = blockIdx.x, pb = blockIdx.y, chunk = blockIdx.z;
    int t = threadIdx.x;
    int px = pb * 256 + t;
    int co_base = chunk * 32;
    int csz = (chunk == 4) ? 2 : 32;
    for (int i = t; i < csz * 256; i += 256) wl[i] = w3[co_base * 256 + i];
    __syncthreads();
    float acc[32];
    #pragma unroll
    for (int j = 0; j < 32; ++j) acc[j] = 0.0f;
    for (int j = 0; j < csz; ++j) acc[j] = b3[co_base + j];
    const float* ap = act2 + (size_t)bn * NCH * NPIX + px;
    if (csz == 32) {
        #pragma unroll 4
        for (int ci = 0; ci < NCH; ++ci) {
            float x = ap[(size_t)ci * NPIX];
            #pragma unroll
            for (int j = 0; j < 32; ++j) acc[j] = fmaf(x, wl[j * 256 + ci], acc[j]);
        }
    } else {
        #pragma unroll 4
        for (int ci = 0; ci < NCH; ++ci) {
            float x = ap[(size_t)ci * NPIX];
            acc[0] = fmaf(x, wl[ci], acc[0]);
            acc[1] = fmaf(x, wl[256 + ci], acc[1]);
        }
    }
    int gp = bn * NPIX + px;
    for (int j = 0; j < csz; ++j) {
        int co = co_base + j;
        if (co == 0)      mu[gp] = acc[j];
        else if (co == 1) ls[gp] = acc[j];
        else              feat_t[(size_t)gp * NOUTC + (co - 2)] = acc[j];
    }
}

// ---- kernel 4: gaussian depth weights + scatter-add into channel-last BEV ----
// one wave per pixel; 4 waves per block.
__global__ __launch_bounds__(256) void splat_kernel(
    const int*   __restrict__ vcode,   // [12][20][2816]
    const float* __restrict__ feat_t,  // [33792][128]
    const float* __restrict__ mu_a,
    const float* __restrict__ ls_a,
    float* __restrict__ bev_tmp,       // [2][65536][128]
    float* __restrict__ mask_out)      // [2][65536]
{
    int wid  = threadIdx.x >> 6;
    int lane = threadIdx.x & 63;
    int gp = blockIdx.x * 4 + wid;     // 0..33791
    int bn = gp / NPIX;
    int hw = gp - bn * NPIX;
    int b  = bn / 6;
    float mu  = mu_a[gp];
    float sig = expf(ls_a[gp]) + 1e-6f;
    float ninv2 = -0.5f / (sig * sig);
    float g[NDEP]; float s = 0.0f;
    #pragma unroll
    for (int d = 0; d < NDEP; ++d) {
        float dv = 1.0f + 3.0f * (float)d;
        float df = dv - mu;
        g[d] = expf(df * df * ninv2);
        s += g[d];
    }
    float inv = 1.0f / (s + 1e-6f);
    float f0 = feat_t[(size_t)gp * NOUTC + lane];
    float f1 = feat_t[(size_t)gp * NOUTC + 64 + lane];
    const int* vp = vcode + (size_t)bn * NDEP * NPIX + hw;
    float* mbase = mask_out + (size_t)b * NVOX;
    float* bbase = bev_tmp + (size_t)b * NVOX * NOUTC;
    #pragma unroll
    for (int d = 0; d < NDEP; ++d) {
        int code = vp[(size_t)d * NPIX];
        if (code >= 0) {
            float wv = g[d] * inv;
            float* p = bbase + (size_t)code * NOUTC;
            atomicAdd(p + lane,      wv * f0);
            atomicAdd(p + 64 + lane, wv * f1);
            if (lane == 0) mbase[code] = 1.0f;
        }
    }
}

// ---- kernel 5: channel-last -> channel-first BEV transpose ----
// block handles 64 voxels x 128 channels through LDS (stride 129: conflict-free).
__global__ __launch_bounds__(256) void transpose_kernel(
    const float* __restrict__ bev_tmp, float* __restrict__ bev_out)
{
    __shared__ float lds[64 * 129];
    int blk = blockIdx.x;              // 0..2047
    int b   = blk >> 10;
    int v0  = (blk & 1023) * 64;
    int t   = threadIdx.x;
    const float* src = bev_tmp + ((size_t)b * NVOX + v0) * NOUTC;
    #pragma unroll
    for (int k = 0; k < 32; ++k) {
        int idx = k * 256 + t;
        int v = idx >> 7, c = idx & 127;
        lds[v * 129 + c] = src[idx];
    }
    __syncthreads();
    float* dst = bev_out + (size_t)b * NOUTC * NVOX + v0;
    #pragma unroll
    for (int k = 0; k < 32; ++k) {
        int idx = k * 256 + t;
        int v = idx & 63, c = idx >> 6;
        dst[(size_t)c * NVOX + v] = lds[v * 129 + c];
    }
}

extern "C" void kernel_launch(void* const* d_in, const int* in_sizes, int n_in,
                              void* d_out, int out_size, void* d_ws, size_t ws_size,
                              hipStream_t stream) {
    const float* c2e_rot    = (const float*)d_in[0];
    const float* c2e_trans  = (const float*)d_in[1];
    const float* intrins    = (const float*)d_in[2];
    const float* post_rot   = (const float*)d_in[3];
    const float* post_trans = (const float*)d_in[4];
    const float* img_feats  = (const float*)d_in[5];
    const float* conv1_w    = (const float*)d_in[6];
    const float* conv1_b    = (const float*)d_in[7];
    const float* bn1_s = (const float*)d_in[8];
    const float* bn1_b = (const float*)d_in[9];
    const float* bn1_m = (const float*)d_in[10];
    const float* bn1_v = (const float*)d_in[11];
    const float* conv2_w = (const float*)d_in[12];
    const float* conv2_b = (const float*)d_in[13];
    const float* bn2_s = (const float*)d_in[14];
    const float* bn2_b = (const float*)d_in[15];
    const float* bn2_m = (const float*)d_in[16];
    const float* bn2_v = (const float*)d_in[17];
    const float* conv3_w = (const float*)d_in[18];
    const float* conv3_b = (const float*)d_in[19];

    float* ws     = (float*)d_ws;
    float* mats   = ws + WS_MATS;
    float* A1     = ws + WS_A1;
    float* C1     = ws + WS_C1;
    float* A2     = ws + WS_A2;
    float* C2     = ws + WS_C2;
    int*   vcode  = (int*)(ws + WS_VCODE);
    float* act1   = ws + WS_ACT1;
    float* act2   = ws + WS_ACT2;
    float* feat_t = ws + WS_FEATT;
    float* mu     = ws + WS_MU;
    float* ls     = ws + WS_LS;
    float* bevtmp = ws + WS_BEVTMP;

    float* bev_out  = (float*)d_out;
    float* mask_out = bev_out + BEV_FLOATS;

    prep_kernel<<<1, 256, 0, stream>>>(c2e_rot, c2e_trans, intrins, post_rot, post_trans,
                                       conv1_b, bn1_s, bn1_b, bn1_m, bn1_v,
                                       conv2_b, bn2_s, bn2_b, bn2_m, bn2_v, ws);
    geom_kernel<<<(NIMG * NDEP * NPIX) / 256, 256, 0, stream>>>(mats, vcode);
    conv3x3_bn_relu<<<dim3(NIMG, 64), 256, 0, stream>>>(img_feats, conv1_w, A1, C1, act1);
    conv3x3_bn_relu<<<dim3(NIMG, 64), 256, 0, stream>>>(act1, conv2_w, A2, C2, act2);
    conv1x1_kernel<<<dim3(NIMG, 11, 5), 256, 0, stream>>>(act2, conv3_w, conv3_b, feat_t, mu, ls);
    // bevtmp aliases act1/act2 -> zero only after conv3 consumed them
    hipMemsetAsync(bevtmp, 0, (size_t)BEV_FLOATS * sizeof(float), stream);
    hipMemsetAsync(d_out, 0, (size_t)out_size * sizeof(float), stream);
    splat_kernel<<<(NIMG * NPIX) / 4, 256, 0, stream>>>(vcode, feat_t, mu, ls, bevtmp, mask_out);
    transpose_kernel<<<2 * (NVOX / 64), 256, 0, stream>>>(bevtmp, bev_out);
}

// Round 2
// 649.879 us; speedup vs baseline: 2.5854x; 2.5854x over previous
//
#include <hip/hip_runtime.h>
#include <math.h>

typedef unsigned short ushort_t;
typedef unsigned int uint_t;

#define NIMG 12        // B*N
#define NCH  256       // FC
#define FH   32
#define FW   88
#define NPIX 2816      // FH*FW
#define NDEP 20        // depth bins: 1,4,...,58
#define NOUTC 128
#define NVOX 65536     // 256*256
#define BEV_FLOATS 16777216u  // 2*128*65536

// ---- workspace layout (BYTE offsets) ----
#define B_MATS   0u          // 12*24 floats = 1152
#define B_A1     4096u       // 256 floats
#define B_C1     5120u
#define B_A2     6144u
#define B_C2     7168u
#define B_MU     8192u       // 33792 floats = 135168
#define B_LS     143360u     // 135168
#define B_VCODE  278528u     // 675840 ints = 2703360
#define B_FEAT   2981888u    // 33792*128 floats = 17301504 -> ends 20283392
#define B_BEV    20283392u   // 67108864 -> ends 87392256 (< 90972160 prev usage)
// inside BEV region (dead before bev memset):
#define B_XBF    20283392u   // 12*2816*256 bf16 = 17301504
#define B_ACT1   37584896u   // 17301504
#define B_ACT2   54886400u   // 17301504
#define B_WSWZ1  72187904u   // 9*8*16*2*512*2 = 2359296
#define B_WSWZ2  74547200u   // 2359296
#define B_WSWZ3  76906496u   // 8*9*2*512*2 = 147456 -> ends 77053952

typedef __attribute__((ext_vector_type(8))) short bf16x8;
typedef __attribute__((ext_vector_type(4))) float floatx4;
typedef __attribute__((ext_vector_type(4))) uint_t u32x4;

__device__ __forceinline__ ushort_t f2bf(float f) {
    uint_t x = __float_as_uint(f);
    return (ushort_t)((x + 0x7fffu + ((x >> 16) & 1u)) >> 16);
}
__device__ __forceinline__ float bf2f(ushort_t u) {
    return __uint_as_float(((uint_t)u) << 16);
}

__device__ __forceinline__ void inv3x3(const float* __restrict__ M, float* __restrict__ o) {
    float a=M[0],b=M[1],c=M[2],d=M[3],e=M[4],f=M[5],g=M[6],h=M[7],i=M[8];
    float A = e*i - f*h;
    float B = c*h - b*i;
    float C = b*f - c*e;
    float D = f*g - d*i;
    float E = a*i - c*g;
    float F = c*d - a*f;
    float G = d*h - e*g;
    float H = b*g - a*h;
    float I = a*e - b*d;
    float det = a*A + b*D + c*G;
    float id = 1.0f / det;
    o[0]=A*id; o[1]=B*id; o[2]=C*id;
    o[3]=D*id; o[4]=E*id; o[5]=F*id;
    o[6]=G*id; o[7]=H*id; o[8]=I*id;
}

// ---- kernel: per-(b,n) matrices + folded BN coefficients ----
__global__ __launch_bounds__(256) void prep_kernel(
    const float* __restrict__ c2e_rot, const float* __restrict__ c2e_trans,
    const float* __restrict__ intrins, const float* __restrict__ post_rot,
    const float* __restrict__ post_trans,
    const float* __restrict__ c1b, const float* __restrict__ s1,
    const float* __restrict__ bb1, const float* __restrict__ m1, const float* __restrict__ v1,
    const float* __restrict__ c2b, const float* __restrict__ s2,
    const float* __restrict__ bb2, const float* __restrict__ m2, const float* __restrict__ v2,
    float* __restrict__ mats, float* __restrict__ A1, float* __restrict__ C1,
    float* __restrict__ A2, float* __restrict__ C2)
{
    int t = threadIdx.x;
    if (t < NIMG) {
        float ip[9], ki[9], comb[9];
        inv3x3(post_rot + t*9, ip);
        inv3x3(intrins  + t*9, ki);
        const float* R = c2e_rot + t*9;
        #pragma unroll
        for (int r = 0; r < 3; ++r)
            #pragma unroll
            for (int c = 0; c < 3; ++c)
                comb[r*3+c] = R[r*3+0]*ki[0*3+c] + R[r*3+1]*ki[1*3+c] + R[r*3+2]*ki[2*3+c];
        float* M = mats + t*24;
        #pragma unroll
        for (int k = 0; k < 9; ++k) { M[k] = ip[k]; M[9+k] = comb[k]; }
        M[18] = c2e_trans[t*3+0]; M[19] = c2e_trans[t*3+1]; M[20] = c2e_trans[t*3+2];
        M[21] = post_trans[t*3+0]; M[22] = post_trans[t*3+1]; M[23] = post_trans[t*3+2];
    }
    {
        float i1 = s1[t] / sqrtf(v1[t] + 1e-3f);
        A1[t] = i1;
        C1[t] = (c1b[t] - m1[t]) * i1 + bb1[t];
        float i2 = s2[t] / sqrtf(v2[t] + 1e-3f);
        A2[t] = i2;
        C2[t] = (c2b[t] - m2[t]) * i2 + bb2[t];
    }
}

// ---- kernel: weight swizzle into MFMA A-fragment order, split hi/lo bf16 ----
// dst layout: [tap][cib][cogrp][2(hi/lo)][64 lanes][8], element:
//   W[co = g*16 + (l&15)][ci = b*32 + (l>>4)*8 + j] (tap t)
__global__ __launch_bounds__(256) void wprep_kernel(
    const float* __restrict__ w, ushort_t* __restrict__ dst,
    int ntap, int ncib, int ncog, int nco, int nci, int total)
{
    int idx = blockIdx.x * 256 + threadIdx.x;
    if (idx >= total) return;
    int j = idx & 7;
    int l = (idx >> 3) & 63;
    int pairidx = idx >> 9;
    int g = pairidx % ncog;
    int b = (pairidx / ncog) % ncib;
    int t = pairidx / (ncog * ncib);
    int co = g * 16 + (l & 15);
    int ci = b * 32 + (l >> 4) * 8 + j;
    float v = 0.0f;
    if (co < nco) v = w[((size_t)co * nci + ci) * ntap + t];
    ushort_t hi = f2bf(v);
    ushort_t lo = f2bf(v - bf2f(hi));
    dst[(size_t)pairidx * 1024 + l * 8 + j]       = hi;
    dst[(size_t)pairidx * 1024 + 512 + l * 8 + j] = lo;
}

// ---- kernel: voxel code per frustum point ----
__global__ __launch_bounds__(256) void geom_kernel(
    const float* __restrict__ mats, int* __restrict__ vcode)
{
    int i = blockIdx.x * 256 + threadIdx.x;   // 0 .. 675839
    if (i >= NIMG * NDEP * NPIX) return;
    int hw  = i % NPIX;
    int tmp = i / NPIX;
    int d   = tmp % NDEP;
    int bn  = tmp / NDEP;
    int h = hw / FW, w = hw - h * FW;
    const float* M = mats + bn * 24;
    float xs = (float)w * (703.0f / 87.0f);
    float ys = (float)h * (255.0f / 31.0f);
    float dv = 1.0f + 3.0f * (float)d;
    float fx = xs - M[21], fy = ys - M[22], fz = dv - M[23];
    float p0 = M[0]*fx + M[1]*fy + M[2]*fz;
    float p1 = M[3]*fx + M[4]*fy + M[5]*fz;
    float p2 = M[6]*fx + M[7]*fy + M[8]*fz;
    p0 *= p2; p1 *= p2;
    float gx = M[ 9]*p0 + M[10]*p1 + M[11]*p2 + M[18];
    float gy = M[12]*p0 + M[13]*p1 + M[14]*p2 + M[19];
    float gz = M[15]*p0 + M[16]*p1 + M[17]*p2 + M[20];
    const float cx = -51.0f - 0.2f, cy = -51.0f - 0.2f, cz = 0.0f - 10.0f;
    int ix = (int)((gx - cx) / 0.4f);
    int iy = (int)((gy - cy) / 0.4f);
    int iz = (int)((gz - cz) / 20.0f);
    bool kept = (ix >= 0) && (ix < 256) && (iy >= 0) && (iy < 256) && (iz == 0);
    vcode[i] = kept ? ((ix << 8) | iy) : -1;
}

// ---- kernel: cast + transpose img_feats fp32 [img][ci][px] -> bf16 [img*px][ci] ----
__global__ __launch_bounds__(256) void cast_transpose_kernel(
    const float* __restrict__ in, ushort_t* __restrict__ out)
{
    __shared__ __align__(16) ushort_t lds[64 * 264];
    int img = blockIdx.y;
    int px0 = blockIdx.x * 64;
    int t = threadIdx.x;
    const float* src = in + (size_t)img * NCH * NPIX;
    int pxl = t & 63;
    int cib = t >> 6;
    #pragma unroll 4
    for (int cc = 0; cc < 64; ++cc) {
        int ci = cc * 4 + cib;
        float v = src[(size_t)ci * NPIX + px0 + pxl];
        lds[pxl * 264 + ci] = f2bf(v);
    }
    __syncthreads();
    int wv = t >> 6, lane = t & 63;
    uint2* outv = (uint2*)out;
    #pragma unroll
    for (int i = 0; i < 16; ++i) {
        int p = wv * 16 + i;
        uint2 val = *(const uint2*)&lds[p * 264 + lane * 4];
        outv[(size_t)(img * NPIX + px0 + p) * 64 + lane] = val;
    }
}

// ---- staging: copy 3 input rows x 88 cols x 32 ci (bf16, 64B chunks) into LDS ----
// LDS layout [3 rows][90 cols][32 ci]; col 0 & 89 and out-of-range rows stay zero.
__device__ __forceinline__ void stage_tile(const u32x4* __restrict__ src4,
                                           ushort_t* __restrict__ ldsb,
                                           int kb, int h, int t)
{
    #pragma unroll
    for (int k = 0; k < 5; ++k) {
        int p = t + k * 256;
        if (p < 1056) {
            int chunk = p >> 2, sub = p & 3;
            int r = chunk / 88;
            int col = chunk - r * 88;
            int hin = h - 1 + r;
            if (hin >= 0 && hin < FH) {
                u32x4 v = src4[(hin * 88 + col) * 32 + kb * 4 + sub];
                *(u32x4*)&ldsb[((r * 90 + col + 1) * 4 + sub) * 8] = v;
            }
        }
    }
}

// ---- kernel: 3x3 conv + BN + ReLU via bf16 MFMA (split-bf16 weights) ----
// grid (img*32 rows, 2 co-groups of 128), block 256 (4 waves).
// wave w: co = cg*128 + w*32 .. +31 (2 m-tiles), N = one row of 88 px (6 overlapping n-tiles).
__global__ __launch_bounds__(256, 3) void conv3x3_mfma(
    const ushort_t* __restrict__ in,     // [img*2816][256] bf16
    const ushort_t* __restrict__ wswz,   // [9][8][16][2][64][8] bf16
    const float* __restrict__ Abn, const float* __restrict__ Cbn,
    ushort_t* __restrict__ out)          // [img*2816][256] bf16
{
    __shared__ __align__(16) ushort_t lds[2][8640];
    int bx = blockIdx.x;            // img*32 + h
    int cg = blockIdx.y;
    int img = bx >> 5, h = bx & 31;
    int t = threadIdx.x;
    int w = t >> 6, l = t & 63;
    int q = l >> 4, c = l & 15;
    const int n0s[6] = {0, 16, 32, 48, 64, 72};

    // zero both LDS buffers (halo stays zero forever)
    for (int i = t; i < 8640; i += 256) ((uint_t*)lds)[i] = 0;

    const u32x4* src4 = (const u32x4*)(in + (size_t)img * NPIX * 256);
    const bf16x8* wsA = (const bf16x8*)wswz;

    floatx4 acc[2][6];
    #pragma unroll
    for (int m = 0; m < 2; ++m)
        #pragma unroll
        for (int n = 0; n < 6; ++n)
            acc[m][n] = (floatx4){0.f, 0.f, 0.f, 0.f};

    int g0 = cg * 8 + w * 2;

    __syncthreads();                 // zeros visible before first stage
    stage_tile(src4, lds[0], 0, h, t);

    int buf = 0;
    for (int kb = 0; kb < 8; ++kb) {
        __syncthreads();
        if (kb < 7) stage_tile(src4, lds[buf ^ 1], kb + 1, h, t);
        const bf16x8* B = (const bf16x8*)lds[buf];
        #pragma unroll
        for (int t9 = 0; t9 < 9; ++t9) {
            int ky = t9 / 3, kx = t9 - ky * 3;
            int pa = (t9 * 8 + kb) * 16;
            bf16x8 a0h = wsA[(size_t)(pa + g0    ) * 128 +      l];
            bf16x8 a0l = wsA[(size_t)(pa + g0    ) * 128 + 64 + l];
            bf16x8 a1h = wsA[(size_t)(pa + g0 + 1) * 128 +      l];
            bf16x8 a1l = wsA[(size_t)(pa + g0 + 1) * 128 + 64 + l];
            #pragma unroll
            for (int n = 0; n < 6; ++n) {
                int col = n0s[n] + kx + c;
                bf16x8 b = B[(ky * 90 + col) * 4 + q];
                acc[0][n] = __builtin_amdgcn_mfma_f32_16x16x32_bf16(a0h, b, acc[0][n], 0, 0, 0);
                acc[0][n] = __builtin_amdgcn_mfma_f32_16x16x32_bf16(a0l, b, acc[0][n], 0, 0, 0);
                acc[1][n] = __builtin_amdgcn_mfma_f32_16x16x32_bf16(a1h, b, acc[1][n], 0, 0, 0);
                acc[1][n] = __builtin_amdgcn_mfma_f32_16x16x32_bf16(a1l, b, acc[1][n], 0, 0, 0);
            }
        }
        buf ^= 1;
    }

    // epilogue: BN + ReLU, store bf16 channel-last
    #pragma unroll
    for (int m = 0; m < 2; ++m) {
        int cob = cg * 128 + w * 32 + m * 16 + q * 4;
        float ba0 = Abn[cob+0], ba1 = Abn[cob+1], ba2 = Abn[cob+2], ba3 = Abn[cob+3];
        float bc0 = Cbn[cob+0], bc1 = Cbn[cob+1], bc2 = Cbn[cob+2], bc3 = Cbn[cob+3];
        #pragma unroll
        for (int n = 0; n < 6; ++n) {
            if (n == 5 && c < 8) continue;   // overlap tile: only cols 80..87
            int col = n0s[n] + c;
            floatx4 v = acc[m][n];
            uint_t lo = (uint_t)f2bf(fmaxf(v[0]*ba0+bc0, 0.f)) | ((uint_t)f2bf(fmaxf(v[1]*ba1+bc1, 0.f)) << 16);
            uint_t hi = (uint_t)f2bf(fmaxf(v[2]*ba2+bc2, 0.f)) | ((uint_t)f2bf(fmaxf(v[3]*ba3+bc3, 0.f)) << 16);
            uint2 val; val.x = lo; val.y = hi;
            *(uint2*)&out[((size_t)img * NPIX + h * 88 + col) * 256 + cob] = val;
        }
    }
}

// ---- kernel: 1x1 conv 256->130 via MFMA (co padded to 144), split mu/ls/feat ----
__global__ __launch_bounds__(256, 4) void gemm1x1_mfma(
    const ushort_t* __restrict__ act2,   // [33792][256] bf16
    const ushort_t* __restrict__ wswz3,  // [8][9][2][64][8] bf16
    const float* __restrict__ b3,
    float* __restrict__ feat, float* __restrict__ mu, float* __restrict__ ls)
{
    int t = threadIdx.x, wv = t >> 6, l = t & 63, q = l >> 4, c = l & 15;
    int n0 = (blockIdx.x * 4 + wv) * 16;
    int px = n0 + c;
    const bf16x8* A = (const bf16x8*)wswz3;
    const bf16x8* B = (const bf16x8*)act2;
    floatx4 acc[9];
    #pragma unroll
    for (int g = 0; g < 9; ++g) acc[g] = (floatx4){0.f, 0.f, 0.f, 0.f};
    for (int kb = 0; kb < 8; ++kb) {
        bf16x8 b = B[(size_t)px * 32 + kb * 4 + q];
        #pragma unroll
        for (int g = 0; g < 9; ++g) {
            size_t pa = (size_t)(kb * 9 + g) * 128;
            acc[g] = __builtin_amdgcn_mfma_f32_16x16x32_bf16(A[pa + l],      b, acc[g], 0, 0, 0);
            acc[g] = __builtin_amdgcn_mfma_f32_16x16x32_bf16(A[pa + 64 + l], b, acc[g], 0, 0, 0);
        }
    }
    #pragma unroll
    for (int g = 0; g < 9; ++g) {
        #pragma unroll
        for (int r = 0; r < 4; ++r) {
            int co = g * 16 + q * 4 + r;
            if (co >= 130) continue;
            float v = acc[g][r] + b3[co];
            if (co == 0)      mu[px] = v;
            else if (co == 1) ls[px] = v;
            else              feat[(size_t)px * 128 + (co - 2)] = v;
        }
    }
}

// ---- kernel: gaussian depth weights + scatter-add into channel-last BEV ----
__global__ __launch_bounds__(256) void splat_kernel(
    const int*   __restrict__ vcode,   // [12][20][2816]
    const float* __restrict__ feat_t,  // [33792][128]
    const float* __restrict__ mu_a,
    const float* __restrict__ ls_a,
    float* __restrict__ bev_tmp,       // [2][65536][128]
    float* __restrict__ mask_out)      // [2][65536]
{
    int wid  = threadIdx.x >> 6;
    int lane = threadIdx.x & 63;
    int gp = blockIdx.x * 4 + wid;     // 0..33791
    int bn = gp / NPIX;
    int hw = gp - bn * NPIX;
    int b  = bn / 6;
    float mu  = mu_a[gp];
    float sig = expf(ls_a[gp]) + 1e-6f;
    float ninv2 = -0.5f / (sig * sig);
    float g[NDEP]; float s = 0.0f;
    #pragma unroll
    for (int d = 0; d < NDEP; ++d) {
        float dv = 1.0f + 3.0f * (float)d;
        float df = dv - mu;
        g[d] = expf(df * df * ninv2);
        s += g[d];
    }
    float inv = 1.0f / (s + 1e-6f);
    float f0 = feat_t[(size_t)gp * NOUTC + lane];
    float f1 = feat_t[(size_t)gp * NOUTC + 64 + lane];
    const int* vp = vcode + (size_t)bn * NDEP * NPIX + hw;
    float* mbase = mask_out + (size_t)b * NVOX;
    float* bbase = bev_tmp + (size_t)b * NVOX * NOUTC;
    #pragma unroll
    for (int d = 0; d < NDEP; ++d) {
        int code = vp[(size_t)d * NPIX];
        if (code >= 0) {
            float wv = g[d] * inv;
            float* p = bbase + (size_t)code * NOUTC;
            atomicAdd(p + lane,      wv * f0);
            atomicAdd(p + 64 + lane, wv * f1);
            if (lane == 0) mbase[code] = 1.0f;
        }
    }
}

// ---- kernel: channel-last -> channel-first BEV transpose ----
__global__ __launch_bounds__(256) void transpose_kernel(
    const float* __restrict__ bev_tmp, float* __restrict__ bev_out)
{
    __shared__ float lds[64 * 129];
    int blk = blockIdx.x;              // 0..2047
    int b   = blk >> 10;
    int v0  = (blk & 1023) * 64;
    int t   = threadIdx.x;
    const float* src = bev_tmp + ((size_t)b * NVOX + v0) * NOUTC;
    #pragma unroll
    for (int k = 0; k < 32; ++k) {
        int idx = k * 256 + t;
        int v = idx >> 7, ch = idx & 127;
        lds[v * 129 + ch] = src[idx];
    }
    __syncthreads();
    float* dst = bev_out + (size_t)b * NOUTC * NVOX + v0;
    #pragma unroll
    for (int k = 0; k < 32; ++k) {
        int idx = k * 256 + t;
        int v = idx & 63, ch = idx >> 6;
        dst[(size_t)ch * NVOX + v] = lds[v * 129 + ch];
    }
}

extern "C" void kernel_launch(void* const* d_in, const int* in_sizes, int n_in,
                              void* d_out, int out_size, void* d_ws, size_t ws_size,
                              hipStream_t stream) {
    const float* c2e_rot    = (const float*)d_in[0];
    const float* c2e_trans  = (const float*)d_in[1];
    const float* intrins    = (const float*)d_in[2];
    const float* post_rot   = (const float*)d_in[3];
    const float* post_trans = (const float*)d_in[4];
    const float* img_feats  = (const float*)d_in[5];
    const float* conv1_w    = (const float*)d_in[6];
    const float* conv1_b    = (const float*)d_in[7];
    const float* bn1_s = (const float*)d_in[8];
    const float* bn1_b = (const float*)d_in[9];
    const float* bn1_m = (const float*)d_in[10];
    const float* bn1_v = (const float*)d_in[11];
    const float* conv2_w = (const float*)d_in[12];
    const float* conv2_b = (const float*)d_in[13];
    const float* bn2_s = (const float*)d_in[14];
    const float* bn2_b = (const float*)d_in[15];
    const float* bn2_m = (const float*)d_in[16];
    const float* bn2_v = (const float*)d_in[17];
    const float* conv3_w = (const float*)d_in[18];
    const float* conv3_b = (const float*)d_in[19];

    char* base = (char*)d_ws;
    float*    mats   = (float*)(base + B_MATS);
    float*    A1     = (float*)(base + B_A1);
    float*    C1     = (float*)(base + B_C1);
    float*    A2     = (float*)(base + B_A2);
    float*    C2     = (float*)(base + B_C2);
    float*    mu     = (float*)(base + B_MU);
    float*    ls     = (float*)(base + B_LS);
    int*      vcode  = (int*)(base + B_VCODE);
    float*    feat   = (float*)(base + B_FEAT);
    float*    bevtmp = (float*)(base + B_BEV);
    ushort_t* xbf    = (ushort_t*)(base + B_XBF);
    ushort_t* act1   = (ushort_t*)(base + B_ACT1);
    ushort_t* act2   = (ushort_t*)(base + B_ACT2);
    ushort_t* wswz1  = (ushort_t*)(base + B_WSWZ1);
    ushort_t* wswz2  = (ushort_t*)(base + B_WSWZ2);
    ushort_t* wswz3  = (ushort_t*)(base + B_WSWZ3);

    float* bev_out  = (float*)d_out;
    float* mask_out = bev_out + BEV_FLOATS;

    prep_kernel<<<1, 256, 0, stream>>>(c2e_rot, c2e_trans, intrins, post_rot, post_trans,
                                       conv1_b, bn1_s, bn1_b, bn1_m, bn1_v,
                                       conv2_b, bn2_s, bn2_b, bn2_m, bn2_v,
                                       mats, A1, C1, A2, C2);
    wprep_kernel<<<2304, 256, 0, stream>>>(conv1_w, wswz1, 9, 8, 16, 256, 256, 589824);
    wprep_kernel<<<2304, 256, 0, stream>>>(conv2_w, wswz2, 9, 8, 16, 256, 256, 589824);
    wprep_kernel<<<144,  256, 0, stream>>>(conv3_w, wswz3, 1, 8,  9, 130, 256, 36864);
    geom_kernel<<<(NIMG * NDEP * NPIX) / 256, 256, 0, stream>>>(mats, vcode);
    cast_transpose_kernel<<<dim3(44, 12), 256, 0, stream>>>(img_feats, xbf);
    conv3x3_mfma<<<dim3(NIMG * 32, 2), 256, 0, stream>>>(xbf,  wswz1, A1, C1, act1);
    conv3x3_mfma<<<dim3(NIMG * 32, 2), 256, 0, stream>>>(act1, wswz2, A2, C2, act2);
    gemm1x1_mfma<<<528, 256, 0, stream>>>(act2, wswz3, conv3_b, feat, mu, ls);
    // act/wswz regions are dead now; zero the aliasing BEV scratch + mask
    hipMemsetAsync(bevtmp, 0, (size_t)BEV_FLOATS * sizeof(float), stream);
    hipMemsetAsync(mask_out, 0, (size_t)2 * NVOX * sizeof(float), stream);
    splat_kernel<<<(NIMG * NPIX) / 4, 256, 0, stream>>>(vcode, feat, mu, ls, bevtmp, mask_out);
    transpose_kernel<<<2 * (NVOX / 64), 256, 0, stream>>>(bevtmp, bev_out);
}